// Round 5
// baseline (349.360 us; speedup 1.0000x reference)
//
#include <hip/hip_runtime.h>
#include <hip/hip_bf16.h>
#include <stdint.h>

// Problem constants
#define L_DIM 1024
#define C_DIM 512       // channels (elements)
#define CB4 256         // fp4 row stride in BYTES (512 elems * 4 bit)
#define N_BATCH 32
#define M_NEG 4096
#define NROWS (N_BATCH * L_DIM) // 32768

typedef float f32x4 __attribute__((ext_vector_type(4)));
typedef int i32x4 __attribute__((ext_vector_type(4)));
typedef int i32x8 __attribute__((ext_vector_type(8)));

// E stored as fp4 e2m1 scaled by 32 (clip at |x|=0.1875 ~ 4.3 sigma);
// e8m0 scale 122 (=2^-5) on both MFMA operands gives exact 1/1024 comp.
#define E4_SCALE 32.0f
#define MX_SCALE 122
#define FMT_FP4 4

// DMA immediate offset must be a compile-time constant -> template param.
template <int GOFF>
__device__ __forceinline__ void gl_lds16(const uint8_t* g, uint8_t* l) {
  __builtin_amdgcn_global_load_lds(
      (const __attribute__((address_space(1))) void*)g,
      (__attribute__((address_space(3))) void*)l, 16, GOFF, 0);
}

// fp4 e2m1 round-to-nearest encode of pre-scaled value.
__device__ __forceinline__ uint32_t fp4_enc(float x) {
  const uint32_t s = (__float_as_uint(x) >> 31) << 3;
  const float a = fabsf(x);
  uint32_t c;
  c = a < 0.25f ? 0u
    : a < 0.75f ? 1u
    : a < 1.25f ? 2u
    : a < 1.75f ? 3u
    : a < 2.5f  ? 4u
    : a < 3.5f  ? 5u
    : a < 5.0f  ? 6u : 7u;
  return s | c;
}

// fp4 operand tuple: HW reads only v[0:3] for FMT_FP4; upper half undef.
__device__ __forceinline__ i32x8 fp4_op(i32x4 d) {
  return __builtin_shufflevector(d, d, 0, 1, 2, 3, -1, -1, -1, -1);
}

// LDS swizzle phase: bank window is 128 B = two 64 B rows -> phase advances
// once per 2 rows. Conflict-free (verified: SQ_LDS_BANK_CONFLICT == 0).
__device__ __forceinline__ int swz(int row) { return (row >> 1) & 3; }

// Counted-vmcnt barrier: wait for the oldest DMA groups only; newer groups
// stay in flight ACROSS the barrier. Safe vs stray compiler loads: any load
// issued after a group only increases the outstanding count, making the wait
// stricter, never weaker. NEVER __syncthreads in the K-loop (drains vmcnt).
#define WAITK(n) asm volatile("s_waitcnt vmcnt(" #n ")\n\ts_barrier" ::: "memory")
// Raw barrier (WAR protection only; no vmcnt drain).
#define BARRIER() asm volatile("s_barrier" ::: "memory")
// LDS-visibility barrier for the epilogue staging (lgkm drain, no vmcnt).
#define LBAR() asm volatile("s_waitcnt lgkmcnt(0)\n\ts_barrier" ::: "memory")

// ---------------------------------------------------------------------------
// Kernel 1: row-wise L2 normalize fp32 [32768, 512] -> fp4 e2m1 (x32 scaled).
// Blocks 0..255 also zero the rowsum+simpos accumulators; block 0 zeroes
// the loss scalar.
// ---------------------------------------------------------------------------
__global__ __launch_bounds__(256) void k_normalize(const float* __restrict__ emb,
                                                   uint8_t* __restrict__ out,
                                                   float* __restrict__ zerobuf,
                                                   float* __restrict__ loss_out) {
  if (blockIdx.x < 256) zerobuf[blockIdx.x * 256 + threadIdx.x] = 0.0f;
  if (blockIdx.x == 0 && threadIdx.x == 0) loss_out[0] = 0.0f;
  const int lane = threadIdx.x & 63;
  const int wave = threadIdx.x >> 6;
  const long row = (long)blockIdx.x * 4 + wave;
  const float4* src = (const float4*)(emb + row * C_DIM);
  float4 v0 = src[2 * lane];
  float4 v1 = src[2 * lane + 1];
  float ss = v0.x * v0.x + v0.y * v0.y + v0.z * v0.z + v0.w * v0.w +
             v1.x * v1.x + v1.y * v1.y + v1.z * v1.z + v1.w * v1.w;
#pragma unroll
  for (int off = 1; off < 64; off <<= 1) ss += __shfl_xor(ss, off, 64);
  const float s = E4_SCALE / fmaxf(sqrtf(ss), 1e-12f);
  uint32_t pk = fp4_enc(v0.x * s)        | (fp4_enc(v0.y * s) << 4) |
                (fp4_enc(v0.z * s) << 8) | (fp4_enc(v0.w * s) << 12) |
                (fp4_enc(v1.x * s) << 16)| (fp4_enc(v1.y * s) << 20) |
                (fp4_enc(v1.z * s) << 24)| (fp4_enc(v1.w * s) << 28);
  ((uint32_t*)(out + row * CB4))[lane] = pk;
}

// ---------------------------------------------------------------------------
// Kernel 2 (FUSED, PERSISTENT): 1024 blocks (= exactly 4/CU, zero tail),
// 10 tiles per block: 2 mode-1 (pos GEMM) + 8 mode-0 (neg GEMM).
// Tile mapping (bijective; every tile's xcd-field == b&7 -> per-XCD L2
// locality preserved; mode-0 chain keeps the SAME A-rows, colBase += 512):
//   b bits: [b9b8 | b7b6b5 | b4b3 | b2b1b0]
//   mode-1 (tiles b, b+1024):  n = (b&7)*4 + ((b>>3)&3);
//     rowB = ((b>>5)&7)*128;  colB = (b>>8)*128 + {0,512}
//   mode-0 (tiles b+2048+1024k, k=0..7): rowB = ((b&7)*32+((b>>3)&31))*128
//     (const per block);  colB = (b>>8)*128 + 512k
// K-pipeline: ONE continuous 2-buffer rotation across all 40 k-steps.
// Steady state: every WAITK(4) waits on a group issued 2 kcomputes earlier;
// next tile's k0/k1 DMAs are in flight during the ENTIRE epilogue of the
// current tile -> cold-start + epilogue exposure paid once per block, not
// once per tile. idx loads for the next tile slot between k2 and k3 issues
// -> that one wait is WAITK(6).
// Epilogues: in-register shfl reduce + 1 KB LDS stage (S2, disjoint from
// A/B buffers so in-flight DMAs are untouched) -> 128 consecutive-address
// atomics per tile (R13's coalesced pattern; R3's scatter-storm avoided).
// ---------------------------------------------------------------------------
__global__ __launch_bounds__(256, 4) void k_gemm_fused(
    const uint8_t* __restrict__ E4, const int* __restrict__ idx,
    const float* __restrict__ W, float* __restrict__ rowsum,
    float* __restrict__ simpos) {
  __shared__ __align__(16) unsigned char smem_raw[33792];
  uint8_t* sA = (uint8_t*)smem_raw;          // [2][128][64B] = 16 KB
  uint8_t* sB = sA + 16384;                  // [2][128][64B] = 16 KB
  float* S2 = (float*)(smem_raw + 32768);    // [4 waves][64 rows] = 1 KB

  const int tid = threadIdx.x;
  const int lane = tid & 63;
  const int wave = tid >> 6;
  const int wm = wave >> 1, wn = wave & 1;
  const int q = lane >> 4, c16 = lane & 15;
  const int b = blockIdx.x;

  // Uniform tile parameters (SALU).
  const long n1   = (long)((b & 7) * 4 + ((b >> 3) & 3));
  const long row1 = (long)((b >> 5) & 7) * 128;
  const long col1 = (long)(b >> 8) * 128;
  const long row0 = (long)((b & 7) * 32 + ((b >> 3) & 31)) * 128;
  const long col0 = (long)(b >> 8) * 128;

  // Per-thread staging constants. Thread covers 16B chunks {tid, 256+tid}:
  // chunk c -> row rw=c>>2, group cb=c&3, swizzled byte off (cb^swz(rw))*16.
  const int rw0 = tid >> 2, rw1 = 64 + (tid >> 2), cb = tid & 3;
  const long off0 = (long)((cb ^ swz(rw0)) * 16);
  const long off1 = (long)((cb ^ swz(rw1)) * 16);
  const long rowAdd0 = (long)rw0 * CB4 + off0;
  const long rowAdd1 = (long)rw1 * CB4 + off1;

  // Staging pointers for the tile whose k0/k1 are (being) issued.
  const uint8_t *pA0, *pA1, *pB0, *pB1;
  {
    const long aB = (n1 * L_DIM + row1) * CB4;
    const long bB = (n1 * L_DIM + col1) * CB4;
    pA0 = E4 + aB + rowAdd0;  pA1 = E4 + aB + rowAdd1;
    pB0 = E4 + bB + rowAdd0;  pB1 = E4 + bB + rowAdd1;
  }

  // Hoisted LDS fragment byte-offsets (loop-invariant, relative to buf).
  int ldsB[4], ldsA[4];
#pragma unroll
  for (int j = 0; j < 4; ++j) {
    const int rowB = wn * 64 + j * 16 + c16;
    ldsB[j] = rowB * 64 + (q ^ swz(rowB)) * 16;
    const int rowA = wm * 64 + j * 16 + c16;
    ldsA[j] = rowA * 64 + (q ^ swz(rowA)) * 16;
  }

  f32x4 acc[4][4] = {};

#define ISS(GOFF, BUF) do { \
    gl_lds16<GOFF>(pA0, sA + (BUF) + tid * 16); \
    gl_lds16<GOFF>(pA1, sA + (BUF) + 4096 + tid * 16); \
    gl_lds16<GOFF>(pB0, sB + (BUF) + tid * 16); \
    gl_lds16<GOFF>(pB1, sB + (BUF) + 4096 + tid * 16); \
  } while (0)

#define ACC0() do { \
    _Pragma("unroll") for (int _i = 0; _i < 4; ++_i) \
    _Pragma("unroll") for (int _j = 0; _j < 4; ++_j) \
      acc[_i][_j] = (f32x4){0.f, 0.f, 0.f, 0.f}; \
  } while (0)

  auto kcompute = [&](int kofs) {
    i32x8 bfr[4];
#pragma unroll
    for (int j = 0; j < 4; ++j)
      bfr[j] = fp4_op(*(const i32x4*)(sB + kofs + ldsB[j]));
    __builtin_amdgcn_s_setprio(1);
#pragma unroll
    for (int i = 0; i < 4; ++i) {
      i32x8 af = fp4_op(*(const i32x4*)(sA + kofs + ldsA[i]));
#pragma unroll
      for (int j = 0; j < 4; ++j)
        acc[i][j] = __builtin_amdgcn_mfma_scale_f32_16x16x128_f8f6f4(
            af, bfr[j], acc[i][j], FMT_FP4, FMT_FP4,
            0, MX_SCALE, 0, MX_SCALE);
    }
    __builtin_amdgcn_s_setprio(0);
  };

  // Mode-0 epilogue: rowsum[row] += sum_col exp(sim). Reduce this wave's
  // half-row in registers (shfl over c16), stage to S2, combine wn-halves,
  // 128 consecutive-address atomics.
  auto epi0 = [&](long ER) {
#pragma unroll
    for (int i = 0; i < 4; ++i)
#pragma unroll
      for (int r = 0; r < 4; ++r) {
        float s = __expf(acc[i][0][r]) + __expf(acc[i][1][r]) +
                  __expf(acc[i][2][r]) + __expf(acc[i][3][r]);
        s += __shfl_xor(s, 1, 64);
        s += __shfl_xor(s, 2, 64);
        s += __shfl_xor(s, 4, 64);
        s += __shfl_xor(s, 8, 64);
        if (c16 == 0) S2[wave * 64 + i * 16 + q * 4 + r] = s;
      }
    LBAR();
    if (tid < 128) {
      const int base = (tid >> 6) * 128 + (tid & 63);
      atomicAdd(&rowsum[ER + tid], S2[base] + S2[base + 64]);
    }
  };

  // Mode-1 epilogue: simpos[n,row] += sum_col W[row,col]*sim (W L2-resident).
  auto epi1 = [&](long ER, long EC, long EN) {
    const float* Wp = W + (ER + wm * 64) * L_DIM + EC + wn * 64 + c16;
#pragma unroll
    for (int i = 0; i < 4; ++i)
#pragma unroll
      for (int r = 0; r < 4; ++r) {
        const float* wr = Wp + (i * 16 + q * 4 + r) * L_DIM;
        float v = acc[i][0][r] * wr[0]  + acc[i][1][r] * wr[16] +
                  acc[i][2][r] * wr[32] + acc[i][3][r] * wr[48];
        v += __shfl_xor(v, 1, 64);
        v += __shfl_xor(v, 2, 64);
        v += __shfl_xor(v, 4, 64);
        v += __shfl_xor(v, 8, 64);
        if (c16 == 0) S2[wave * 64 + i * 16 + q * 4 + r] = v;
      }
    LBAR();
    if (tid < 128) {
      const int base = (tid >> 6) * 128 + (tid & 63);
      atomicAdd(&simpos[EN * L_DIM + ER + tid], S2[base] + S2[base + 64]);
    }
  };

  // Prologue: tile0.k0 -> buf0, tile0.k1 -> buf1.  Queue invariant entering
  // each tile: [k0(4), k1(4)] outstanding.
  ISS(0, 0);
  ISS(64, 8192);

  // ================= tile 0 (mode-1), next = mode-1 =================
  WAITK(4); kcompute(0);    BARRIER(); ISS(128, 0);
  WAITK(4); kcompute(8192); BARRIER(); ISS(192, 8192);
  WAITK(4); kcompute(0);    BARRIER();
  pB0 += 512 * CB4; pB1 += 512 * CB4;   // m1 tile 1: same n/rows, colB += 512
  ISS(0, 0);
  WAITK(4); kcompute(8192); BARRIER(); ISS(64, 8192);
  epi1(row1, col1, n1);
  ACC0();

  // ================= tile 1 (mode-1), next = mode-0 =================
  WAITK(4); kcompute(0);    BARRIER(); ISS(128, 0);
  WAITK(4); kcompute(8192); BARRIER();
  {
    const int i0 = idx[col0 + rw0];     // next tile's B rows (slot: k2 < idx < k3)
    const int i1 = idx[col0 + rw1];
    ISS(192, 8192);
    WAITK(6); kcompute(0);  BARRIER(); // k2 done: 6 newer (idx 2 + k3 4)
    pA0 = E4 + row0 * CB4 + rowAdd0;   // mode-0 A rows (const for the chain)
    pA1 = E4 + row0 * CB4 + rowAdd1;
    pB0 = E4 + (long)i0 * CB4 + off0;
    pB1 = E4 + (long)i1 * CB4 + off1;
    ISS(0, 0);
  }
  WAITK(4); kcompute(8192); BARRIER(); ISS(64, 8192);
  epi1(row1, col1 + 512, n1);
  ACC0();

  // ================= tiles 2..8 (mode-0), next = mode-0 =================
  long nxcol = col0 + 512;
#pragma unroll 1
  for (int it = 0; it < 7; ++it) {
    WAITK(4); kcompute(0);    BARRIER(); ISS(128, 0);
    WAITK(4); kcompute(8192); BARRIER();
    {
      const int j0 = idx[nxcol + rw0];
      const int j1 = idx[nxcol + rw1];
      ISS(192, 8192);
      WAITK(6); kcompute(0);  BARRIER();
      pB0 = E4 + (long)j0 * CB4 + off0;   // pA unchanged (same A rows)
      pB1 = E4 + (long)j1 * CB4 + off1;
      ISS(0, 0);
    }
    WAITK(4); kcompute(8192); BARRIER(); ISS(64, 8192);
    epi0(row0);
    ACC0();
    nxcol += 512;
  }

  // ================= tile 9 (mode-0), last =================
  WAITK(4); kcompute(0);    BARRIER(); ISS(128, 0);
  WAITK(4); kcompute(8192); BARRIER(); ISS(192, 8192);
  WAITK(4); kcompute(0);    BARRIER();
  WAITK(0); kcompute(8192);
  epi0(row0);

#undef ISS
#undef ACC0
}

// ---------------------------------------------------------------------------
// Kernel 3: 128-block finalize; out[0] pre-zeroed by k_normalize.
// loss = mean over rows of log(rowsum_neg + exp(simpos)) - simpos
// ---------------------------------------------------------------------------
__global__ __launch_bounds__(256) void k_finalize(const float* __restrict__ rowsum,
                                                  const float* __restrict__ simpos,
                                                  float* __restrict__ out) {
  const int gid = blockIdx.x * 256 + threadIdx.x;  // one row per thread
  const float sp = simpos[gid];
  float v = __logf(rowsum[gid] + __expf(sp)) - sp;
#pragma unroll
  for (int off = 1; off < 64; off <<= 1) v += __shfl_xor(v, off, 64);
  __shared__ float ws[4];
  if ((threadIdx.x & 63) == 0) ws[threadIdx.x >> 6] = v;
  __syncthreads();
  if (threadIdx.x == 0)
    atomicAdd(out, (ws[0] + ws[1] + ws[2] + ws[3]) * (1.0f / (float)NROWS));
}

// ---------------------------------------------------------------------------
// Workspace layout (bytes):
//   [0,       8388608)  E fp4 [32768, 256 B]   (x32 scaled e2m1)
//   [8388608, 8519680)  rowsum fp32 [32768]
//   [8519680, 8650752)  simpos fp32 [32768]    (contiguous with rowsum)
// ---------------------------------------------------------------------------
extern "C" void kernel_launch(void* const* d_in, const int* in_sizes, int n_in,
                              void* d_out, int out_size, void* d_ws, size_t ws_size,
                              hipStream_t stream) {
  const float* emb = (const float*)d_in[0];
  const float* weight = (const float*)d_in[1];
  const int* negidx = (const int*)d_in[2];
  float* out = (float*)d_out;
  char* ws = (char*)d_ws;

  uint8_t* E4 = (uint8_t*)ws;
  float* rowsum = (float*)(ws + 8388608);
  float* simpos = (float*)(ws + 8519680);

  k_normalize<<<NROWS / 4, 256, 0, stream>>>(emb, E4, rowsum, out);
  k_gemm_fused<<<1024, 256, 0, stream>>>(E4, negidx, weight, rowsum, simpos);
  k_finalize<<<NROWS / 256, 256, 0, stream>>>(rowsum, simpos, out);
}

// Round 8
// 160.579 us; speedup vs baseline: 2.1756x; 2.1756x over previous
//
#include <hip/hip_runtime.h>
#include <hip/hip_bf16.h>
#include <stdint.h>

// Problem constants
#define L_DIM 1024
#define C_DIM 512       // channels (elements)
#define CB4 256         // fp4 row stride in BYTES (512 elems * 4 bit)
#define N_BATCH 32
#define M_NEG 4096
#define NROWS (N_BATCH * L_DIM) // 32768

typedef float f32x4 __attribute__((ext_vector_type(4)));
typedef int i32x4 __attribute__((ext_vector_type(4)));
typedef int i32x8 __attribute__((ext_vector_type(8)));

// E stored as fp4 e2m1 scaled by 32 (clip at |x|=0.1875 ~ 4.3 sigma);
// e8m0 scale 122 (=2^-5) on both MFMA operands gives exact 1/1024 comp.
#define E4_SCALE 32.0f
#define MX_SCALE 122
#define FMT_FP4 4

// DMA immediate offset must be a compile-time constant -> template param.
template <int GOFF>
__device__ __forceinline__ void gl_lds16(const uint8_t* g, uint8_t* l) {
  __builtin_amdgcn_global_load_lds(
      (const __attribute__((address_space(1))) void*)g,
      (__attribute__((address_space(3))) void*)l, 16, GOFF, 0);
}

// fp4 e2m1 round-to-nearest encode of pre-scaled value.
__device__ __forceinline__ uint32_t fp4_enc(float x) {
  const uint32_t s = (__float_as_uint(x) >> 31) << 3;
  const float a = fabsf(x);
  uint32_t c;
  c = a < 0.25f ? 0u
    : a < 0.75f ? 1u
    : a < 1.25f ? 2u
    : a < 1.75f ? 3u
    : a < 2.5f  ? 4u
    : a < 3.5f  ? 5u
    : a < 5.0f  ? 6u : 7u;
  return s | c;
}

// fp4 operand tuple: HW reads only v[0:3] for FMT_FP4; upper half undef.
__device__ __forceinline__ i32x8 fp4_op(i32x4 d) {
  return __builtin_shufflevector(d, d, 0, 1, 2, 3, -1, -1, -1, -1);
}

// LDS swizzle phase: bank window is 128 B = two 64 B rows -> phase advances
// once per 2 rows. Conflict-free (verified: SQ_LDS_BANK_CONFLICT == 0).
__device__ __forceinline__ int swz(int row) { return (row >> 1) & 3; }

// Counted-vmcnt barrier (T4). SOUNDNESS NOTES (R6/R7 lessons):
//  * A counted wait is sound iff the modeled DMA groups are issued in the
//    modeled ORDER. Extra/stray vmem ops anywhere only make the wait
//    stricter (in-order retirement retires oldest first); a wait is only
//    unsound if ops are MISSING or groups are INTERLEAVED by the compiler.
//  * Two global_load_lds groups in the SAME fence region write non-aliasing
//    LDS -> LLVM may interleave them -> "retire oldest 4" retires a mix.
//    FIX: an empty memory-clobber asm FENCE between adjacent groups.
#define WAITK(n) asm volatile("s_waitcnt vmcnt(" #n ")\n\ts_barrier" ::: "memory")
// Raw barrier (WAR protection only; no vmcnt drain).
#define BARRIER() asm volatile("s_barrier" ::: "memory")
// Compiler-only fence: pins DMA group issue order; emits no instruction.
#define FENCE() asm volatile("" ::: "memory")

// ---------------------------------------------------------------------------
// Kernel 1: row-wise L2 normalize fp32 [32768, 512] -> fp4 e2m1 (x32 scaled).
// R8: lane-contiguous float4 loads (two coalesced 1KB/wave sweeps; the old
// src[2*lane] pattern was 16B at 32B stride = half-used segments) + two u16
// stores (element e -> nibble e -> byte e/2; elements 4l.. -> bytes 2l..).
// Blocks 0..255 also zero the rowsum+simpos accumulators; block 0 zeroes
// the loss scalar.
// ---------------------------------------------------------------------------
__global__ __launch_bounds__(256) void k_normalize(const float* __restrict__ emb,
                                                   uint8_t* __restrict__ out,
                                                   float* __restrict__ zerobuf,
                                                   float* __restrict__ loss_out) {
  if (blockIdx.x < 256) zerobuf[blockIdx.x * 256 + threadIdx.x] = 0.0f;
  if (blockIdx.x == 0 && threadIdx.x == 0) loss_out[0] = 0.0f;
  const int lane = threadIdx.x & 63;
  const int wave = threadIdx.x >> 6;
  const long row = (long)blockIdx.x * 4 + wave;
  const float4* src = (const float4*)(emb + row * C_DIM);
  float4 v0 = src[lane];        // elements 4*lane   .. 4*lane+3
  float4 v1 = src[lane + 64];   // elements 256+4*lane ..
  float ss = v0.x * v0.x + v0.y * v0.y + v0.z * v0.z + v0.w * v0.w +
             v1.x * v1.x + v1.y * v1.y + v1.z * v1.z + v1.w * v1.w;
#pragma unroll
  for (int off = 1; off < 64; off <<= 1) ss += __shfl_xor(ss, off, 64);
  const float s = E4_SCALE / fmaxf(sqrtf(ss), 1e-12f);
  const uint32_t lo = fp4_enc(v0.x * s)        | (fp4_enc(v0.y * s) << 4) |
                      (fp4_enc(v0.z * s) << 8) | (fp4_enc(v0.w * s) << 12);
  const uint32_t hi = fp4_enc(v1.x * s)        | (fp4_enc(v1.y * s) << 4) |
                      (fp4_enc(v1.z * s) << 8) | (fp4_enc(v1.w * s) << 12);
  ((uint16_t*)(out + row * CB4))[lane] = (uint16_t)lo;
  ((uint16_t*)(out + row * CB4 + 128))[lane] = (uint16_t)hi;
}

// ---------------------------------------------------------------------------
// Kernel 2 (FUSED): 10240-block dispatch, both GEMMs. R4 structure (the
// verified best: 70.0 us, absmax 0), hardened:
//  * K-loop: 32 KB LDS, 2 k-step tiles double-buffered, counted vmcnt(4)
//    prefetch depth 1, raw s_barrier for WAR (no vmcnt drain).
//  * FENCE() between the prologue's two DMA groups (see WAITK notes): the
//    only same-region group pair; pins issue order so WAITK(4) retires
//    exactly k0. All other groups are already fence-separated.
//  * T5 s_setprio(1) around the MFMA cluster: co-resident blocks are at
//    different tiles (de-phased) -> the regime where setprio pays (m191);
//    cannot affect correctness.
//  * Epilogue: combine wn-halves in LDS, then COALESCED atomics (128
//    consecutive addresses). R3's scattered atomics caused an 8x
//    WRITE_SIZE storm -> never again.
// XCD swizzle (dispatch round-robin xcd ~= bid&7):
//   mode 1 (bid<2048):  xcd=bid&7; slot=bid>>3; n=xcd*4+(slot&3);
//       inner=slot>>2; rowTile=inner&7, colTile=inner>>3.  (~1 MB/XCD)
//   mode 0 (bid>=2048): t=bid-2048; xcd=t&7; slot=t>>3;
//       rowTile=xcd*32+(slot&31), colTile=slot>>5.  (A 1MB + B 1MB /XCD)
// ---------------------------------------------------------------------------
__global__ __launch_bounds__(256, 4) void k_gemm_fused(
    const uint8_t* __restrict__ E4, const int* __restrict__ idx,
    const float* __restrict__ W, float* __restrict__ rowsum,
    float* __restrict__ simpos) {
  __shared__ __align__(16) unsigned char smem_raw[32768];
  uint8_t* sA = (uint8_t*)smem_raw;          // [2][128][64B] = 16 KB
  uint8_t* sB = sA + 16384;                  // [2][128][64B] = 16 KB

  const int tid = threadIdx.x;
  const int lane = tid & 63;
  const int wave = tid >> 6;
  const int wm = wave >> 1, wn = wave & 1;
  const int q = lane >> 4, c16 = lane & 15;

  const int bid = blockIdx.x;
  const bool is0 = bid >= 2048;
  long rowBase, colBase, n = 0;
  if (is0) {
    const int t = bid - 2048;
    const int xcd = t & 7, slot = t >> 3;
    rowBase = (long)(xcd * 32 + (slot & 31)) * 128;
    colBase = (long)(slot >> 5) * 128;
  } else {
    const int xcd = bid & 7, slot = bid >> 3;
    n = xcd * 4 + (slot & 3);
    const int inner = slot >> 2;          // 0..63
    rowBase = (long)(inner & 7) * 128;
    colBase = (long)(inner >> 3) * 128;
  }
  const long aBase = is0 ? rowBase : n * L_DIM + rowBase;

  // Staging base pointers (2 A + 2 B); per-kstep advance is the ks*64
  // IMMEDIATE offset on the DMA (template) -> zero K-loop address VALU.
  const uint8_t* pA[2];
  const uint8_t* pB[2];
#pragma unroll
  for (int r = 0; r < 2; ++r) {
    const int c = r * 256 + tid;          // 16B chunk 0..511
    const int rw = c >> 2, cb = c & 3;    // row 0..127, group 0..3
    pA[r] = E4 + (aBase + rw) * CB4 + (cb ^ swz(rw)) * 16;
    const long bRow = is0 ? (long)idx[colBase + rw] : n * L_DIM + colBase + rw;
    pB[r] = E4 + bRow * CB4 + (cb ^ swz(rw)) * 16;
  }

  // Hoisted LDS fragment byte-offsets (loop-invariant, relative to kstep buf).
  int ldsB[4], ldsA[4];
#pragma unroll
  for (int j = 0; j < 4; ++j) {
    const int rowB = wn * 64 + j * 16 + c16;
    ldsB[j] = rowB * 64 + (q ^ swz(rowB)) * 16;
    const int rowA = wm * 64 + j * 16 + c16;
    ldsA[j] = rowA * 64 + (q ^ swz(rowA)) * 16;
  }

  f32x4 acc[4][4] = {};

  auto kcompute = [&](int kofs) {
    i32x8 bfr[4];
#pragma unroll
    for (int j = 0; j < 4; ++j)
      bfr[j] = fp4_op(*(const i32x4*)(sB + kofs + ldsB[j]));
    __builtin_amdgcn_s_setprio(1);
#pragma unroll
    for (int i = 0; i < 4; ++i) {
      i32x8 af = fp4_op(*(const i32x4*)(sA + kofs + ldsA[i]));
#pragma unroll
      for (int j = 0; j < 4; ++j)
        acc[i][j] = __builtin_amdgcn_mfma_scale_f32_16x16x128_f8f6f4(
            af, bfr[j], acc[i][j], FMT_FP4, FMT_FP4,
            0, MX_SCALE, 0, MX_SCALE);
    }
    __builtin_amdgcn_s_setprio(0);
  };

  // Prologue: k0 -> buf0, FENCE, k1 -> buf1. The fence pins group order so
  // WAITK(4)'s "oldest 4" is exactly k0 (see soundness notes above).
  gl_lds16<0>(pA[0], sA + tid * 16);
  gl_lds16<0>(pA[1], sA + (256 + tid) * 16);
  gl_lds16<0>(pB[0], sB + tid * 16);
  gl_lds16<0>(pB[1], sB + (256 + tid) * 16);
  FENCE();
  gl_lds16<64>(pA[0], sA + 8192 + tid * 16);
  gl_lds16<64>(pA[1], sA + 8192 + (256 + tid) * 16);
  gl_lds16<64>(pB[0], sB + 8192 + tid * 16);
  gl_lds16<64>(pB[1], sB + 8192 + (256 + tid) * 16);

  WAITK(4);          // k0 landed (k1's 4 still in flight)
  kcompute(0);
  BARRIER();         // all waves done reading buf0 -> safe to overwrite
  gl_lds16<128>(pA[0], sA + tid * 16);          // k2 -> buf0
  gl_lds16<128>(pA[1], sA + (256 + tid) * 16);
  gl_lds16<128>(pB[0], sB + tid * 16);
  gl_lds16<128>(pB[1], sB + (256 + tid) * 16);
  WAITK(4);          // k1 landed (k2's 4 in flight)
  kcompute(8192);
  BARRIER();         // WAR buf1
  gl_lds16<192>(pA[0], sA + 8192 + tid * 16);   // k3 -> buf1
  gl_lds16<192>(pA[1], sA + 8192 + (256 + tid) * 16);
  gl_lds16<192>(pB[0], sB + 8192 + tid * 16);
  gl_lds16<192>(pB[1], sB + 8192 + (256 + tid) * 16);
  WAITK(4);          // k2 landed (k3's 4 in flight)
  kcompute(0);
  WAITK(0);          // k3 landed
  kcompute(8192);
  __syncthreads();   // all waves done reading sA/sB -> epilogue reuses LDS

  // Epilogue (R13 structure). C/D layout: col = c16, row = q*4 + reg.
  if (is0) {
    float* S = (float*)smem_raw;  // [4 waves][64 rows][pad 20] = 20480 B
#pragma unroll
    for (int i = 0; i < 4; ++i)
#pragma unroll
      for (int r = 0; r < 4; ++r) {
        const float s = __expf(acc[i][0][r]) + __expf(acc[i][1][r]) +
                        __expf(acc[i][2][r]) + __expf(acc[i][3][r]);
        S[wave * 1280 + (i * 16 + q * 4 + r) * 20 + c16] = s;
      }
    __syncthreads();
    if (tid < 128) {
      const int wm2 = tid >> 6, row64 = tid & 63;  // global row = rowBase+tid
      const float* p0 = (const float*)S + (wm2 * 2 + 0) * 1280 + row64 * 20;
      const float* p1 = (const float*)S + (wm2 * 2 + 1) * 1280 + row64 * 20;
      float4 t0 = ((const float4*)p0)[0], t1 = ((const float4*)p0)[1];
      float4 t2 = ((const float4*)p0)[2], t3 = ((const float4*)p0)[3];
      float4 u0 = ((const float4*)p1)[0], u1 = ((const float4*)p1)[1];
      float4 u2 = ((const float4*)p1)[2], u3 = ((const float4*)p1)[3];
      float v = t0.x + t0.y + t0.z + t0.w + t1.x + t1.y + t1.z + t1.w +
                t2.x + t2.y + t2.z + t2.w + t3.x + t3.y + t3.z + t3.w +
                u0.x + u0.y + u0.z + u0.w + u1.x + u1.y + u1.z + u1.w +
                u2.x + u2.y + u2.z + u2.w + u3.x + u3.y + u3.z + u3.w;
      atomicAdd(&rowsum[rowBase + tid], v);
    }
  } else {
    float* G = (float*)smem_raw;  // [32 rows][pad 132] fp32 = 16896 B / pass
#pragma unroll
    for (int p = 0; p < 4; ++p) {  // 32-row passes
      if (wm == (p >> 1)) {
#pragma unroll
        for (int ii = 0; ii < 2; ++ii) {
          const int i = (p & 1) * 2 + ii;
#pragma unroll
          for (int j = 0; j < 4; ++j)
#pragma unroll
            for (int r = 0; r < 4; ++r)
              G[(ii * 16 + q * 4 + r) * 132 + wn * 64 + j * 16 + c16] =
                  acc[i][j][r];
        }
      }
      __syncthreads();
      {
        const int rr = tid >> 3;    // 0..31
        const int chunk = tid & 7;  // 16-float chunks
        const long krow = rowBase + p * 32 + rr;
        float v = 0.0f;
#pragma unroll
        for (int u = 0; u < 4; ++u) {
          const float4 g =
              *(const float4*)(G + rr * 132 + chunk * 16 + u * 4);
          const float4 w4 = *(const float4*)(W + krow * L_DIM + colBase +
                                             chunk * 16 + u * 4);
          v += g.x * w4.x + g.y * w4.y + g.z * w4.z + g.w * w4.w;
        }
        v += __shfl_xor(v, 1, 64);
        v += __shfl_xor(v, 2, 64);
        v += __shfl_xor(v, 4, 64);
        if (chunk == 0) atomicAdd(&simpos[n * L_DIM + krow], v);
      }
      __syncthreads();
    }
  }
}

// ---------------------------------------------------------------------------
// Kernel 3: 128-block finalize; out[0] pre-zeroed by k_normalize.
// loss = mean over rows of log(rowsum_neg + exp(simpos)) - simpos
// ---------------------------------------------------------------------------
__global__ __launch_bounds__(256) void k_finalize(const float* __restrict__ rowsum,
                                                  const float* __restrict__ simpos,
                                                  float* __restrict__ out) {
  const int gid = blockIdx.x * 256 + threadIdx.x;  // one row per thread
  const float sp = simpos[gid];
  float v = __logf(rowsum[gid] + __expf(sp)) - sp;
#pragma unroll
  for (int off = 1; off < 64; off <<= 1) v += __shfl_xor(v, off, 64);
  __shared__ float ws[4];
  if ((threadIdx.x & 63) == 0) ws[threadIdx.x >> 6] = v;
  __syncthreads();
  if (threadIdx.x == 0)
    atomicAdd(out, (ws[0] + ws[1] + ws[2] + ws[3]) * (1.0f / (float)NROWS));
}

// ---------------------------------------------------------------------------
// Workspace layout (bytes):
//   [0,       8388608)  E fp4 [32768, 256 B]   (x32 scaled e2m1)
//   [8388608, 8519680)  rowsum fp32 [32768]
//   [8519680, 8650752)  simpos fp32 [32768]    (contiguous with rowsum)
// ---------------------------------------------------------------------------
extern "C" void kernel_launch(void* const* d_in, const int* in_sizes, int n_in,
                              void* d_out, int out_size, void* d_ws, size_t ws_size,
                              hipStream_t stream) {
  const float* emb = (const float*)d_in[0];
  const float* weight = (const float*)d_in[1];
  const int* negidx = (const int*)d_in[2];
  float* out = (float*)d_out;
  char* ws = (char*)d_ws;

  uint8_t* E4 = (uint8_t*)ws;
  float* rowsum = (float*)(ws + 8388608);
  float* simpos = (float*)(ws + 8519680);

  k_normalize<<<NROWS / 4, 256, 0, stream>>>(emb, E4, rowsum, out);
  k_gemm_fused<<<10240, 256, 0, stream>>>(E4, negidx, weight, rowsum, simpos);
  k_finalize<<<NROWS / 256, 256, 0, stream>>>(rowsum, simpos, out);
}